// Round 4
// baseline (190.964 us; speedup 1.0000x reference)
//
#include <hip/hip_runtime.h>

typedef __bf16 bf16;
typedef __bf16 bf16_4 __attribute__((ext_vector_type(4)));
typedef __bf16 bf16_8 __attribute__((ext_vector_type(8)));
typedef float f32_4 __attribute__((ext_vector_type(4)));

// async global->LDS, 16B per lane; LDS dest must be wave-uniform base + lane*16
#define GLDS16(g, l) \
  __builtin_amdgcn_global_load_lds((const __attribute__((address_space(1))) unsigned int*)(g), \
                                   (__attribute__((address_space(3))) unsigned int*)(l), 16, 0, 0)

// ---------------- fused f32 -> bf16 convert (grid-stride) ----------------
__global__ __launch_bounds__(256) void convert_all(
    const float* __restrict__ x, const float* __restrict__ wq, const float* __restrict__ wk,
    const float* __restrict__ wv, const float* __restrict__ wo,
    bf16* __restrict__ xb, bf16* __restrict__ wqb, bf16* __restrict__ wkb,
    bf16* __restrict__ wvb, bf16* __restrict__ wob)
{
    for (int i = blockIdx.x * 256 + threadIdx.x; i < 2097152; i += 2048 * 256) {
        const float* s; bf16* d; int off;
        if (i < 1048576) { s = x; d = xb; off = i; }
        else {
            int j = i - 1048576;
            int sel = j >> 18;
            off = j & 262143;
            s = (sel == 0) ? wq : (sel == 1) ? wk : (sel == 2) ? wv : wo;
            d = (sel == 0) ? wqb : (sel == 1) ? wkb : (sel == 2) ? wvb : wob;
        }
        float4 v = reinterpret_cast<const float4*>(s)[off];
        bf16_4 o; o.x = (bf16)v.x; o.y = (bf16)v.y; o.z = (bf16)v.z; o.w = (bf16)v.w;
        reinterpret_cast<bf16_4*>(d)[off] = o;
    }
}

// ---- legacy single-buffer GEMM core (used by scores_tr only: BM=128, KU=1, NW=4) ----
template<int BM, int KU, int NW>
__device__ __forceinline__ void gemm_core(
    const bf16* __restrict__ Ab, int lda,
    const bf16* __restrict__ Wb, int ldw,
    int K, int m0, int n0, int tid,
    bf16* As, bf16* Bs,
    f32_4 (&acc)[(BM == 128) ? 4 : 2][(BM == 128) ? 4 : 2])
{
    constexpr int MI = (BM == 128) ? 4 : 2;
    constexpr int NJ = (BM == 128) ? 4 : 2;
    constexpr int ITA = (BM * 8) / (NW * 64);     // A 16B-groups per lane per ku
    constexpr int ITB = 1024 / (NW * 64);         // B 16B-groups per lane per ku
    const int lane = tid & 63;
    const int wave = tid >> 6;
    const int l15  = lane & 15;
    const int quad = lane >> 4;
    const int WM = (BM == 128) ? (wave >> 1) * 64 : (wave >> 2) * 32;
    const int WN = (BM == 128) ? (wave & 1) * 64 : (wave & 3) * 32;

#pragma unroll
    for (int i = 0; i < MI; i++)
#pragma unroll
        for (int j = 0; j < NJ; j++) acc[i][j] = (f32_4)(0.0f);

    for (int k0 = 0; k0 < K; k0 += 64 * KU) {
#pragma unroll
        for (int ku = 0; ku < KU; ++ku) {
            bf16* Asu = As + ku * BM * 64;
            bf16* Bsu = Bs + ku * 128 * 64;
            int kk = k0 + ku * 64;
#pragma unroll
            for (int it = 0; it < ITA; ++it) {
                int p = wave * (BM * 8 / NW) + it * 64 + lane;
                int r = p >> 3;
                int q = (p & 7) ^ (r & 7);
                GLDS16(Ab + (long long)(m0 + r) * lda + kk + q * 8, Asu + p * 8);
            }
#pragma unroll
            for (int it = 0; it < ITB; ++it) {
                int p = wave * (1024 / NW) + it * 64 + lane;
                int r = p >> 3;
                int q = (p & 7) ^ (r & 7);
                GLDS16(Wb + (long long)(n0 + r) * ldw + kk + q * 8, Bsu + p * 8);
            }
        }
        __syncthreads();

#pragma unroll
        for (int ku = 0; ku < KU; ++ku) {
            bf16* Asu = As + ku * BM * 64;
            bf16* Bsu = Bs + ku * 128 * 64;
#pragma unroll
            for (int kh = 0; kh < 2; ++kh) {
                bf16_8 af[MI], bfr[NJ];
#pragma unroll
                for (int t = 0; t < MI; ++t) {
                    int r = WM + t * 16 + l15;
                    int q = (kh * 4 + quad) ^ (r & 7);
                    af[t] = *reinterpret_cast<const bf16_8*>(&Asu[r * 64 + q * 8]);
                }
#pragma unroll
                for (int j = 0; j < NJ; ++j) {
                    int r = WN + j * 16 + l15;
                    int q = (kh * 4 + quad) ^ (r & 7);
                    bfr[j] = *reinterpret_cast<const bf16_8*>(&Bsu[r * 64 + q * 8]);
                }
#pragma unroll
                for (int i = 0; i < MI; ++i)
#pragma unroll
                    for (int j = 0; j < NJ; ++j)
                        acc[i][j] = __builtin_amdgcn_mfma_f32_16x16x32_bf16(af[i], bfr[j], acc[i][j], 0, 0, 0);
            }
        }
        __syncthreads();
    }
}

// ======== 2-phase double-buffered 64x128 GEMM pieces (8 waves, wave-tile 32x32) ========
// Per buffer: As 64x64 (8KB), Bs 128x64 (16KB).  3 GLDS16 per wave per k-64 tile.
__device__ __forceinline__ void stage_ab64(
    const bf16* __restrict__ Ab, long long lda,
    const bf16* __restrict__ Wb, long long ldw,
    int m0, int n0, int kk, int wave, int lane,
    bf16* Asb, bf16* Bsb)
{
    {
        int p = wave * 64 + lane;                 // 512 slots x 8 bf16 = 64x64
        int r = p >> 3, q = (p & 7) ^ (r & 7);
        GLDS16(Ab + (long long)(m0 + r) * lda + kk + q * 8, Asb + p * 8);
    }
#pragma unroll
    for (int it = 0; it < 2; ++it) {
        int p = wave * 128 + it * 64 + lane;      // 1024 slots x 8 bf16 = 128x64
        int r = p >> 3, q = (p & 7) ^ (r & 7);
        GLDS16(Wb + (long long)(n0 + r) * ldw + kk + q * 8, Bsb + p * 8);
    }
}

__device__ __forceinline__ void mma64(
    const bf16* Asb, const bf16* Bsb, int WM, int WN, int l15, int quad,
    f32_4 (&acc)[2][2])
{
#pragma unroll
    for (int kh = 0; kh < 2; ++kh) {
        bf16_8 af[2], bfr[2];
#pragma unroll
        for (int t = 0; t < 2; ++t) {
            int r = WM + t * 16 + l15;
            int q = (kh * 4 + quad) ^ (r & 7);
            af[t] = *reinterpret_cast<const bf16_8*>(&Asb[r * 64 + q * 8]);
        }
#pragma unroll
        for (int j = 0; j < 2; ++j) {
            int r = WN + j * 16 + l15;
            int q = (kh * 4 + quad) ^ (r & 7);
            bfr[j] = *reinterpret_cast<const bf16_8*>(&Bsb[r * 64 + q * 8]);
        }
#pragma unroll
        for (int i = 0; i < 2; ++i)
#pragma unroll
            for (int j = 0; j < 2; ++j)
                acc[i][j] = __builtin_amdgcn_mfma_f32_16x16x32_bf16(af[i], bfr[j], acc[i][j], 0, 0, 0);
    }
}

// full double-buffered K-loop: NT k-64 tiles, counted vmcnt(3) keeps next tile in flight
template<int NT>
__device__ __forceinline__ void gemm_db64(
    const bf16* __restrict__ Ab, long long lda,
    const bf16* __restrict__ Wb, long long ldw,
    int m0, int n0, int tid, bf16* As, bf16* Bs,   // As[2][4096], Bs[2][8192]
    f32_4 (&acc)[2][2])
{
    const int lane = tid & 63, wave = tid >> 6, l15 = lane & 15, quad = lane >> 4;
    const int WM = (wave >> 2) * 32, WN = (wave & 3) * 32;
#pragma unroll
    for (int i = 0; i < 2; i++)
#pragma unroll
        for (int j = 0; j < 2; j++) acc[i][j] = (f32_4)(0.0f);

    stage_ab64(Ab, lda, Wb, ldw, m0, n0, 0, wave, lane, As, Bs);
    for (int t = 0; t < NT; ++t) {
        const int cur = t & 1;
        if (t + 1 < NT) {
            stage_ab64(Ab, lda, Wb, ldw, m0, n0, (t + 1) * 64, wave, lane,
                       As + (cur ^ 1) * 4096, Bs + (cur ^ 1) * 8192);
            asm volatile("s_waitcnt vmcnt(3)" ::: "memory");   // tile t landed; t+1 in flight
        } else {
            asm volatile("s_waitcnt vmcnt(0)" ::: "memory");
        }
        __builtin_amdgcn_s_barrier();
        mma64(As + cur * 4096, Bs + cur * 8192, WM, WN, l15, quad, acc);
        asm volatile("s_waitcnt lgkmcnt(0)" ::: "memory");     // my LDS reads done
        __builtin_amdgcn_s_barrier();                          // buf may be overwritten
    }
}

// -------- merged projections: V full (written TRANSPOSED into vt) + Q/K head-1 --------
// V epilogue writes vt[b][h*64+d][t] directly:
//   output element (m,n):  b=m>>11, h=(m&2047)>>7, t=(m&127)*16 + (n>>6), d=n&63
// (same bijection the old scores_tr LDS transpose implemented; v_bf eliminated)
__global__ __launch_bounds__(512) void proj_merged(
    const bf16* __restrict__ x_bf,
    const bf16* __restrict__ wv_bf, const float* __restrict__ bv, bf16* __restrict__ vt,
    const bf16* __restrict__ wq_bf, const float* __restrict__ bq, bf16* __restrict__ qh1,
    const bf16* __restrict__ wk_bf, const float* __restrict__ bk, bf16* __restrict__ kh1)
{
    __shared__ alignas(16) bf16 As[2 * 4096];
    __shared__ alignas(16) bf16 Bs[2 * 8192];
    const int tid = threadIdx.x;
    const int lane = tid & 63, wave = tid >> 6, l15 = lane & 15, quad = lane >> 4;
    const int n0 = blockIdx.x * 128;

    int m0;
    const bf16* Ab; const bf16* Wb; const float* bvec; bf16* op;
    long long obase;
    bool isV;
    int y = blockIdx.y;
    if (y < 64) { m0 = y * 64; Ab = x_bf; Wb = wv_bf; bvec = bv; op = vt; obase = 0; isV = true; }
    else {
        int sub = y - 64;
        int batch = (sub >> 1) & 1;
        int sel = sub >> 2;
        m0 = (sub & 1) * 64;
        Ab = x_bf + (long long)batch * 2097152LL + 131072LL;   // rows 128..255 of batch slab
        Wb = sel ? wk_bf : wq_bf;
        bvec = sel ? bk : bq;
        op = sel ? kh1 : qh1;
        obase = (long long)batch * 131072LL;
        isV = false;
    }

    f32_4 acc[2][2];
    gemm_db64<16>(Ab, 1024, Wb, 1024, m0, n0, tid, As, Bs, acc);

    const int WM = (wave >> 2) * 32;
    const int WN = (wave & 3) * 32;
    if (isV) {
        // transposed scatter into vt
        long long vbase = (long long)(m0 >> 11) * 2097152LL;
        int h = (m0 & 2047) >> 7;
#pragma unroll
        for (int i = 0; i < 2; i++)
#pragma unroll
            for (int j = 0; j < 2; j++)
#pragma unroll
                for (int rg = 0; rg < 4; rg++) {
                    int m = m0 + WM + i * 16 + quad * 4 + rg;
                    int n = n0 + WN + j * 16 + l15;
                    float v = acc[i][j][rg] + bvec[n];
                    op[vbase + (long long)(h * 64 + (n & 63)) * 2048 + (m & 127) * 16 + (n >> 6)] = (bf16)v;
                }
    } else {
#pragma unroll
        for (int i = 0; i < 2; i++)
#pragma unroll
            for (int j = 0; j < 2; j++)
#pragma unroll
                for (int rg = 0; rg < 4; rg++) {
                    int m = m0 + WM + i * 16 + quad * 4 + rg;
                    int n = n0 + WN + j * 16 + l15;
                    op[obase + (long long)m * 1024 + n] = (bf16)(acc[i][j][rg] + bvec[n]);
                }
    }
}

// -------- scores head-1 + exp + row partials (BK=64, K=64) --------
__global__ __launch_bounds__(256) void scores_tr(
    const bf16* __restrict__ qh1, const bf16* __restrict__ kh1,
    const float* __restrict__ slopes,
    bf16* __restrict__ pb, float* __restrict__ spart)
{
    __shared__ alignas(16) char smem[32768];
    bf16* As = (bf16*)smem;
    bf16* Bs = (bf16*)(smem + 16384);
    const int tid = threadIdx.x;
    const int lane = tid & 63, wave = tid >> 6, l15 = lane & 15, quad = lane >> 4;
    const int n0 = blockIdx.x * 128;
    const int m0 = blockIdx.y * 128;
    const int z  = blockIdx.z;

    f32_4 acc[4][4];
    gemm_core<128, 1, 4>(qh1 + (long long)z * 131072LL, 64,
                         kh1 + (long long)z * 131072LL, 64, 64, m0, n0, tid, As, Bs, acc);

    const int WM = (wave >> 1) * 64;
    const int WN = (wave & 1) * 64;
    const float slope = slopes[1];
    long long obase = (long long)z * 4194304LL;
#pragma unroll
    for (int i = 0; i < 4; i++) {
#pragma unroll
        for (int rg = 0; rg < 4; rg++) {
            int m = m0 + WM + i * 16 + quad * 4 + rg;
            float rowpart = 0.0f;
#pragma unroll
            for (int j = 0; j < 4; j++) {
                int n = n0 + WN + j * 16 + l15;
                float v = acc[i][j][rg] * 0.125f - slope * fabsf((float)(m - n));
                float e = __expf(v);
                rowpart += e;
                pb[obase + (long long)m * 2048 + n] = (bf16)e;
            }
            rowpart += __shfl_xor(rowpart, 1, 64);
            rowpart += __shfl_xor(rowpart, 2, 64);
            rowpart += __shfl_xor(rowpart, 4, 64);
            rowpart += __shfl_xor(rowpart, 8, 64);
            if (l15 == 0)
                spart[((long long)z * 2048 + m) * 32 + (n0 >> 6) + (WN >> 6)] = rowpart;
        }
    }
}

// -------- PV fused: 2-phase DB, counted vmcnt; rsinv prologue + probs_f in-loop -------
__global__ __launch_bounds__(512) void pv_fused(
    const bf16* __restrict__ pb, const bf16* __restrict__ vt,
    const float* __restrict__ spart,
    bf16* __restrict__ attn, float* __restrict__ probs_f)
{
    __shared__ alignas(16) bf16 As[2 * 4096];
    __shared__ alignas(16) bf16 Bs[2 * 8192];
    __shared__ float rs[64];
    const int tid = threadIdx.x;
    const int lane = tid & 63, wave = tid >> 6, l15 = lane & 15, quad = lane >> 4;
    const int nx = blockIdx.x;          // n-tile AND probs k-slice index (both 8-wide)
    const int n0 = nx * 128;
    const int m0 = blockIdx.y * 64;
    const int z  = blockIdx.z;
    const int WM = (wave >> 2) * 32, WN = (wave & 3) * 32;

    const bf16* Ab = pb + (long long)z * 4194304LL;
    const bf16* Wb = vt + (long long)z * 2097152LL;

    // kick off tile-0 loads, then compute rs while they fly
    stage_ab64(Ab, 2048, Wb, 2048, m0, n0, 0, wave, lane, As, Bs);

    // prologue: rs[r] = 1 / sum_j spart[z*2048+m0+r][j]  (64 rows, 8 threads per row)
    {
        int r = tid >> 3, part = tid & 7;
        const float* sp = spart + ((long long)z * 2048 + m0 + r) * 32 + part * 4;
        float4 a = *reinterpret_cast<const float4*>(sp);
        float v = a.x + a.y + a.z + a.w;
        v += __shfl_xor(v, 1, 64);
        v += __shfl_xor(v, 2, 64);
        v += __shfl_xor(v, 4, 64);
        if (part == 0) rs[r] = 1.0f / v;
    }

    f32_4 acc[2][2];
#pragma unroll
    for (int i = 0; i < 2; i++)
#pragma unroll
        for (int j = 0; j < 2; j++) acc[i][j] = (f32_4)(0.0f);

    for (int t = 0; t < 32; ++t) {
        const int cur = t & 1;
        if (t + 1 < 32) {
            stage_ab64(Ab, 2048, Wb, 2048, m0, n0, (t + 1) * 64, wave, lane,
                       As + (cur ^ 1) * 4096, Bs + (cur ^ 1) * 8192);
            asm volatile("s_waitcnt vmcnt(3)" ::: "memory");
        } else {
            asm volatile("s_waitcnt vmcnt(0)" ::: "memory");
        }
        __builtin_amdgcn_s_barrier();   // tile t ready (all waves); also publishes rs at t=0

        // write probs_f (f32, normalized) when this k-64 tile is in our 256-col k-slice
        if ((t >> 2) == nx) {
            const bf16* Asu = As + cur * 4096;
            int s = tid;                     // 512 threads cover 64x64 tile (8 bf16 each)
            int r = s >> 3, q = s & 7;
            bf16_8 e = *reinterpret_cast<const bf16_8*>(&Asu[r * 64 + (q ^ (r & 7)) * 8]);
            float inv = rs[r];
            float4 o0, o1;
            o0.x = (float)e[0] * inv; o0.y = (float)e[1] * inv;
            o0.z = (float)e[2] * inv; o0.w = (float)e[3] * inv;
            o1.x = (float)e[4] * inv; o1.y = (float)e[5] * inv;
            o1.z = (float)e[6] * inv; o1.w = (float)e[7] * inv;
            long long base = ((long long)z * 2048 + m0 + r) * 2048 + t * 64 + q * 8;
            *reinterpret_cast<float4*>(&probs_f[base])     = o0;
            *reinterpret_cast<float4*>(&probs_f[base + 4]) = o1;
        }

        mma64(As + cur * 4096, Bs + cur * 8192, WM, WN, l15, quad, acc);

        asm volatile("s_waitcnt lgkmcnt(0)" ::: "memory");
        __builtin_amdgcn_s_barrier();
    }

    // epilogue: scale by rs[row], scatter to flat attn layout
    long long obase = (long long)z * 2097152LL;
#pragma unroll
    for (int i = 0; i < 2; i++)
#pragma unroll
        for (int j = 0; j < 2; j++)
#pragma unroll
            for (int rg = 0; rg < 4; rg++) {
                int ml = WM + i * 16 + quad * 4 + rg;
                int m = m0 + ml;
                int n = n0 + WN + j * 16 + l15;
                float v = acc[i][j][rg] * rs[ml];
                long long off = obase + ((long long)(n >> 6)) * 131072LL + (long long)m * 64 + (n & 63);
                attn[off] = (bf16)v;
            }
}

// -------- out projection: 2-phase DB, counted vmcnt; f32 out + bias --------
__global__ __launch_bounds__(512) void out_proj(
    const bf16* __restrict__ attn, const bf16* __restrict__ wo_bf,
    const float* __restrict__ bo, float* __restrict__ out_f)
{
    __shared__ alignas(16) bf16 As[2 * 4096];
    __shared__ alignas(16) bf16 Bs[2 * 8192];
    const int tid = threadIdx.x;
    const int lane = tid & 63, wave = tid >> 6, l15 = lane & 15, quad = lane >> 4;
    const int n0 = blockIdx.x * 128;
    const int m0 = blockIdx.y * 64;

    f32_4 acc[2][2];
    gemm_db64<16>(attn, 1024, wo_bf, 1024, m0, n0, tid, As, Bs, acc);

    const int WM = (wave >> 2) * 32;
    const int WN = (wave & 3) * 32;
#pragma unroll
    for (int i = 0; i < 2; i++)
#pragma unroll
        for (int j = 0; j < 2; j++)
#pragma unroll
            for (int rg = 0; rg < 4; rg++) {
                int m = m0 + WM + i * 16 + quad * 4 + rg;
                int n = n0 + WN + j * 16 + l15;
                out_f[(long long)m * 1024 + n] = acc[i][j][rg] + bo[n];
            }
}

// ---------------- launcher: 5 launches ----------------
extern "C" void kernel_launch(void* const* d_in, const int* in_sizes, int n_in,
                              void* d_out, int out_size, void* d_ws, size_t ws_size,
                              hipStream_t stream) {
    const float* x      = (const float*)d_in[0];
    const float* Wq     = (const float*)d_in[1];
    const float* bq     = (const float*)d_in[2];
    const float* Wk     = (const float*)d_in[3];
    const float* bk     = (const float*)d_in[4];
    const float* Wv     = (const float*)d_in[5];
    const float* bv     = (const float*)d_in[6];
    const float* Wo     = (const float*)d_in[7];
    const float* bo     = (const float*)d_in[8];
    const float* slopes = (const float*)d_in[9];

    // B=2, S=2048, E=1024, H=16, hd=64
    char* w = (char*)d_ws;
    bf16* x_bf  = (bf16*)w;  w += 4096LL * 1024 * 2;
    bf16* wq_bf = (bf16*)w;  w += 1024LL * 1024 * 2;
    bf16* wk_bf = (bf16*)w;  w += 1024LL * 1024 * 2;
    bf16* wv_bf = (bf16*)w;  w += 1024LL * 1024 * 2;
    bf16* wo_bf = (bf16*)w;  w += 1024LL * 1024 * 2;
    bf16* qh1   = (bf16*)w;  w += 2LL * 131072 * 2;
    bf16* kh1   = (bf16*)w;  w += 2LL * 131072 * 2;
    bf16* vt    = (bf16*)w;  w += 2LL * 1024 * 2048 * 2;
    bf16* attn  = (bf16*)w;  w += 4096LL * 1024 * 2;
    bf16* pb    = (bf16*)w;  w += 2LL * 2048 * 2048 * 2;
    float* spart = (float*)w; w += 4096LL * 32 * 4;

    float* out_f   = (float*)d_out;                // (B,S,E)
    float* probs_f = (float*)d_out + 4194304LL;    // (B,1,S,S)

    // 1) converts
    convert_all<<<2048, 256, 0, stream>>>(x, Wq, Wk, Wv, Wo, x_bf, wq_bf, wk_bf, wv_bf, wo_bf);

    // 2) merged projections: V full (direct transposed write to vt) + Q/K head-1
    proj_merged<<<dim3(8, 72, 1), 512, 0, stream>>>(
        x_bf, wv_bf, bv, vt, wq_bf, bq, qh1, wk_bf, bk, kh1);

    // 3) scores + exp + spart
    scores_tr<<<dim3(16, 16, 2), 256, 0, stream>>>(qh1, kh1, slopes, pb, spart);

    // 4) PV fused: 2-phase DB; rsinv from spart, probs_f (d_out), attn scatter
    pv_fused<<<dim3(8, 32, 2), 512, 0, stream>>>(pb, vt, spart, attn, probs_f);

    // 5) out projection -> d_out (2-phase DB)
    out_proj<<<dim3(8, 64, 1), 512, 0, stream>>>(attn, wo_bf, bo, out_f);
}

// Round 6
// 168.418 us; speedup vs baseline: 1.1339x; 1.1339x over previous
//
#include <hip/hip_runtime.h>

typedef __bf16 bf16;
typedef __bf16 bf16_4 __attribute__((ext_vector_type(4)));
typedef __bf16 bf16_8 __attribute__((ext_vector_type(8)));
typedef float f32_4 __attribute__((ext_vector_type(4)));

// async global->LDS, 16B per lane; LDS dest must be wave-uniform base + lane*16
#define GLDS16(g, l) \
  __builtin_amdgcn_global_load_lds((const __attribute__((address_space(1))) unsigned int*)(g), \
                                   (__attribute__((address_space(3))) unsigned int*)(l), 16, 0, 0)

// ---------------- fused f32 -> bf16 convert (grid-stride) ----------------
__global__ __launch_bounds__(256) void convert_all(
    const float* __restrict__ x, const float* __restrict__ wq, const float* __restrict__ wk,
    const float* __restrict__ wv, const float* __restrict__ wo,
    bf16* __restrict__ xb, bf16* __restrict__ wqb, bf16* __restrict__ wkb,
    bf16* __restrict__ wvb, bf16* __restrict__ wob)
{
    for (int i = blockIdx.x * 256 + threadIdx.x; i < 2097152; i += 2048 * 256) {
        const float* s; bf16* d; int off;
        if (i < 1048576) { s = x; d = xb; off = i; }
        else {
            int j = i - 1048576;
            int sel = j >> 18;
            off = j & 262143;
            s = (sel == 0) ? wq : (sel == 1) ? wk : (sel == 2) ? wv : wo;
            d = (sel == 0) ? wqb : (sel == 1) ? wkb : (sel == 2) ? wvb : wob;
        }
        float4 v = reinterpret_cast<const float4*>(s)[off];
        bf16_4 o; o.x = (bf16)v.x; o.y = (bf16)v.y; o.z = (bf16)v.z; o.w = (bf16)v.w;
        reinterpret_cast<bf16_4*>(d)[off] = o;
    }
}

// ---- legacy single-buffer GEMM core (used by scores_tr only: BM=128, KU=1, NW=4) ----
template<int BM, int KU, int NW>
__device__ __forceinline__ void gemm_core(
    const bf16* __restrict__ Ab, int lda,
    const bf16* __restrict__ Wb, int ldw,
    int K, int m0, int n0, int tid,
    bf16* As, bf16* Bs,
    f32_4 (&acc)[(BM == 128) ? 4 : 2][(BM == 128) ? 4 : 2])
{
    constexpr int MI = (BM == 128) ? 4 : 2;
    constexpr int NJ = (BM == 128) ? 4 : 2;
    constexpr int ITA = (BM * 8) / (NW * 64);     // A 16B-groups per lane per ku
    constexpr int ITB = 1024 / (NW * 64);         // B 16B-groups per lane per ku
    const int lane = tid & 63;
    const int wave = tid >> 6;
    const int l15  = lane & 15;
    const int quad = lane >> 4;
    const int WM = (BM == 128) ? (wave >> 1) * 64 : (wave >> 2) * 32;
    const int WN = (BM == 128) ? (wave & 1) * 64 : (wave & 3) * 32;

#pragma unroll
    for (int i = 0; i < MI; i++)
#pragma unroll
        for (int j = 0; j < NJ; j++) acc[i][j] = (f32_4)(0.0f);

    for (int k0 = 0; k0 < K; k0 += 64 * KU) {
#pragma unroll
        for (int ku = 0; ku < KU; ++ku) {
            bf16* Asu = As + ku * BM * 64;
            bf16* Bsu = Bs + ku * 128 * 64;
            int kk = k0 + ku * 64;
#pragma unroll
            for (int it = 0; it < ITA; ++it) {
                int p = wave * (BM * 8 / NW) + it * 64 + lane;
                int r = p >> 3;
                int q = (p & 7) ^ (r & 7);
                GLDS16(Ab + (long long)(m0 + r) * lda + kk + q * 8, Asu + p * 8);
            }
#pragma unroll
            for (int it = 0; it < ITB; ++it) {
                int p = wave * (1024 / NW) + it * 64 + lane;
                int r = p >> 3;
                int q = (p & 7) ^ (r & 7);
                GLDS16(Wb + (long long)(n0 + r) * ldw + kk + q * 8, Bsu + p * 8);
            }
        }
        __syncthreads();

#pragma unroll
        for (int ku = 0; ku < KU; ++ku) {
            bf16* Asu = As + ku * BM * 64;
            bf16* Bsu = Bs + ku * 128 * 64;
#pragma unroll
            for (int kh = 0; kh < 2; ++kh) {
                bf16_8 af[MI], bfr[NJ];
#pragma unroll
                for (int t = 0; t < MI; ++t) {
                    int r = WM + t * 16 + l15;
                    int q = (kh * 4 + quad) ^ (r & 7);
                    af[t] = *reinterpret_cast<const bf16_8*>(&Asu[r * 64 + q * 8]);
                }
#pragma unroll
                for (int j = 0; j < NJ; ++j) {
                    int r = WN + j * 16 + l15;
                    int q = (kh * 4 + quad) ^ (r & 7);
                    bfr[j] = *reinterpret_cast<const bf16_8*>(&Bsu[r * 64 + q * 8]);
                }
#pragma unroll
                for (int i = 0; i < MI; ++i)
#pragma unroll
                    for (int j = 0; j < NJ; ++j)
                        acc[i][j] = __builtin_amdgcn_mfma_f32_16x16x32_bf16(af[i], bfr[j], acc[i][j], 0, 0, 0);
            }
        }
        __syncthreads();
    }
}

// ======== 2-phase double-buffered 64x128 GEMM pieces (8 waves, wave-tile 32x32) ========
// Per buffer: As 64x64 (8KB), Bs 128x64 (16KB).  3 GLDS16 per wave per k-64 tile.
__device__ __forceinline__ void stage_ab64(
    const bf16* __restrict__ Ab, long long lda,
    const bf16* __restrict__ Wb, long long ldw,
    int m0, int n0, int kk, int wave, int lane,
    bf16* Asb, bf16* Bsb)
{
    {
        int p = wave * 64 + lane;                 // 512 slots x 8 bf16 = 64x64
        int r = p >> 3, q = (p & 7) ^ (r & 7);
        GLDS16(Ab + (long long)(m0 + r) * lda + kk + q * 8, Asb + p * 8);
    }
#pragma unroll
    for (int it = 0; it < 2; ++it) {
        int p = wave * 128 + it * 64 + lane;      // 1024 slots x 8 bf16 = 128x64
        int r = p >> 3, q = (p & 7) ^ (r & 7);
        GLDS16(Wb + (long long)(n0 + r) * ldw + kk + q * 8, Bsb + p * 8);
    }
}

__device__ __forceinline__ void mma64(
    const bf16* Asb, const bf16* Bsb, int WM, int WN, int l15, int quad,
    f32_4 (&acc)[2][2])
{
#pragma unroll
    for (int kh = 0; kh < 2; ++kh) {
        bf16_8 af[2], bfr[2];
#pragma unroll
        for (int t = 0; t < 2; ++t) {
            int r = WM + t * 16 + l15;
            int q = (kh * 4 + quad) ^ (r & 7);
            af[t] = *reinterpret_cast<const bf16_8*>(&Asb[r * 64 + q * 8]);
        }
#pragma unroll
        for (int j = 0; j < 2; ++j) {
            int r = WN + j * 16 + l15;
            int q = (kh * 4 + quad) ^ (r & 7);
            bfr[j] = *reinterpret_cast<const bf16_8*>(&Bsb[r * 64 + q * 8]);
        }
#pragma unroll
        for (int i = 0; i < 2; ++i)
#pragma unroll
            for (int j = 0; j < 2; ++j)
                acc[i][j] = __builtin_amdgcn_mfma_f32_16x16x32_bf16(af[i], bfr[j], acc[i][j], 0, 0, 0);
    }
}

// full double-buffered K-loop: NT k-64 tiles, counted vmcnt(3) keeps next tile in flight
template<int NT>
__device__ __forceinline__ void gemm_db64(
    const bf16* __restrict__ Ab, long long lda,
    const bf16* __restrict__ Wb, long long ldw,
    int m0, int n0, int tid, bf16* As, bf16* Bs,   // As[2][4096], Bs[2][8192]
    f32_4 (&acc)[2][2])
{
    const int lane = tid & 63, wave = tid >> 6, l15 = lane & 15, quad = lane >> 4;
    const int WM = (wave >> 2) * 32, WN = (wave & 3) * 32;
#pragma unroll
    for (int i = 0; i < 2; i++)
#pragma unroll
        for (int j = 0; j < 2; j++) acc[i][j] = (f32_4)(0.0f);

    stage_ab64(Ab, lda, Wb, ldw, m0, n0, 0, wave, lane, As, Bs);
    for (int t = 0; t < NT; ++t) {
        const int cur = t & 1;
        if (t + 1 < NT) {
            stage_ab64(Ab, lda, Wb, ldw, m0, n0, (t + 1) * 64, wave, lane,
                       As + (cur ^ 1) * 4096, Bs + (cur ^ 1) * 8192);
            asm volatile("s_waitcnt vmcnt(3)" ::: "memory");   // tile t landed; t+1 in flight
        } else {
            asm volatile("s_waitcnt vmcnt(0)" ::: "memory");
        }
        __builtin_amdgcn_s_barrier();
        mma64(As + cur * 4096, Bs + cur * 8192, WM, WN, l15, quad, acc);
        asm volatile("s_waitcnt lgkmcnt(0)" ::: "memory");     // my LDS reads done
        __builtin_amdgcn_s_barrier();                          // buf may be overwritten
    }
}

// -------- merged projections: V full + Q/K head-1 (2-phase DB, 512 thr / 8 waves) -----
// XCD-aware tile remap: lin = x + 8y (XCD = lin&7); XCD c owns y' = c*9 + (s%9), x' = s/9
// so the 8 blocks sharing an A-panel (same y', all x') colocate on one XCD L2.
__global__ __launch_bounds__(512) void proj_merged(
    const bf16* __restrict__ x_bf,
    const bf16* __restrict__ wv_bf, const float* __restrict__ bv, bf16* __restrict__ v_bf,
    const bf16* __restrict__ wq_bf, const float* __restrict__ bq, bf16* __restrict__ qh1,
    const bf16* __restrict__ wk_bf, const float* __restrict__ bk, bf16* __restrict__ kh1)
{
    __shared__ alignas(16) bf16 As[2 * 4096];
    __shared__ alignas(16) bf16 Bs[2 * 8192];
    const int tid = threadIdx.x;
    const int lane = tid & 63, wave = tid >> 6, l15 = lane & 15, quad = lane >> 4;

    int lin = blockIdx.x + 8 * blockIdx.y;      // 0..575
    int c = lin & 7, s = lin >> 3;              // c = XCD slot, s = 0..71
    int y = c * 9 + (s % 9);                    // 0..71 (bijective)
    const int n0 = (s / 9) * 128;               // 0..7 -> n-tile

    int m0;
    const bf16* Ab; const bf16* Wb; const float* bvec; bf16* op;
    long long obase;
    if (y < 64) { m0 = y * 64; Ab = x_bf; Wb = wv_bf; bvec = bv; op = v_bf; obase = 0; }
    else {
        int sub = y - 64;
        int batch = (sub >> 1) & 1;
        int sel = sub >> 2;
        m0 = (sub & 1) * 64;
        Ab = x_bf + (long long)batch * 2097152LL + 131072LL;   // rows 128..255 of batch slab
        Wb = sel ? wk_bf : wq_bf;
        bvec = sel ? bk : bq;
        op = sel ? kh1 : qh1;
        obase = (long long)batch * 131072LL;
    }

    f32_4 acc[2][2];
    gemm_db64<16>(Ab, 1024, Wb, 1024, m0, n0, tid, As, Bs, acc);

    const int WM = (wave >> 2) * 32;
    const int WN = (wave & 3) * 32;
#pragma unroll
    for (int i = 0; i < 2; i++)
#pragma unroll
        for (int j = 0; j < 2; j++)
#pragma unroll
            for (int rg = 0; rg < 4; rg++) {
                int m = m0 + WM + i * 16 + quad * 4 + rg;
                int n = n0 + WN + j * 16 + l15;
                op[obase + (long long)m * 1024 + n] = (bf16)(acc[i][j][rg] + bvec[n]);
            }
}

// -------- scores head-1 + exp + row partials, THEN inline V transpose (BK=64, K=64) ---
__global__ __launch_bounds__(256) void scores_tr(
    const bf16* __restrict__ qh1, const bf16* __restrict__ kh1,
    const float* __restrict__ slopes,
    bf16* __restrict__ pb, float* __restrict__ spart,
    const unsigned short* __restrict__ v_bf, unsigned short* __restrict__ vt)
{
    __shared__ alignas(16) char smem[32768];
    bf16* As = (bf16*)smem;
    bf16* Bs = (bf16*)(smem + 16384);
    const int tid = threadIdx.x;
    const int lane = tid & 63, wave = tid >> 6, l15 = lane & 15, quad = lane >> 4;
    const int n0 = blockIdx.x * 128;
    const int m0 = blockIdx.y * 128;
    const int z  = blockIdx.z;

    f32_4 acc[4][4];
    gemm_core<128, 1, 4>(qh1 + (long long)z * 131072LL, 64,
                         kh1 + (long long)z * 131072LL, 64, 64, m0, n0, tid, As, Bs, acc);

    const int WM = (wave >> 1) * 64;
    const int WN = (wave & 1) * 64;
    const float slope = slopes[1];
    long long obase = (long long)z * 4194304LL;
#pragma unroll
    for (int i = 0; i < 4; i++) {
#pragma unroll
        for (int rg = 0; rg < 4; rg++) {
            int m = m0 + WM + i * 16 + quad * 4 + rg;
            float rowpart = 0.0f;
#pragma unroll
            for (int j = 0; j < 4; j++) {
                int n = n0 + WN + j * 16 + l15;
                float v = acc[i][j][rg] * 0.125f - slope * fabsf((float)(m - n));
                float e = __expf(v);
                rowpart += e;
                pb[obase + (long long)m * 2048 + n] = (bf16)e;
            }
            rowpart += __shfl_xor(rowpart, 1, 64);
            rowpart += __shfl_xor(rowpart, 2, 64);
            rowpart += __shfl_xor(rowpart, 4, 64);
            rowpart += __shfl_xor(rowpart, 8, 64);
            if (l15 == 0)
                spart[((long long)z * 2048 + m) * 32 + (n0 >> 6) + (WN >> 6)] = rowpart;
        }
    }

    // ---- inline V transpose (flat-reshape mapping), 2 of 1024 tiles per block ----
    unsigned short* tile = (unsigned short*)smem;    // As region free after gemm_core
    int flat = z * 256 + blockIdx.y * 16 + blockIdx.x;   // 0..511
#pragma unroll
    for (int uu = 0; uu < 2; ++uu) {
        int u = flat * 2 + uu;                           // 0..1023
        int k0 = (u & 31) * 64, h = (u >> 5) & 15, b = u >> 9;
        const unsigned short* src = v_bf + (long long)b * 2097152LL + (long long)h * 131072LL;
#pragma unroll
        for (int p = 0; p < 8; p++) {
            int idx = tid + p * 256;
            int k = idx >> 5, dc = idx & 31;
            ushort2 w = *reinterpret_cast<const ushort2*>(&src[(long long)(k0 + k) * 64 + dc * 2]);
            tile[(dc * 2) * 66 + k]     = w.x;
            tile[(dc * 2 + 1) * 66 + k] = w.y;
        }
        __syncthreads();
        unsigned short* dst = vt + (long long)b * 2097152LL + (long long)h * 64 * 2048LL + k0;
#pragma unroll
        for (int p = 0; p < 8; p++) {
            int idx = tid + p * 256;
            int d = idx >> 5, kc = idx & 31;
            ushort2 w;
            w.x = tile[d * 66 + kc * 2];
            w.y = tile[d * 66 + kc * 2 + 1];
            *reinterpret_cast<ushort2*>(&dst[(long long)d * 2048 + kc * 2]) = w;
        }
        __syncthreads();
    }
}

// -------- PV fused: 2-phase DB, counted vmcnt; rsinv prologue + probs_f in-loop -------
// XCD-aware tile remap: lin = x + 8y (XCD = lin&7); XCD c owns y' = c*4 + (s&3), x' = s>>2
__global__ __launch_bounds__(512) void pv_fused(
    const bf16* __restrict__ pb, const bf16* __restrict__ vt,
    const float* __restrict__ spart,
    bf16* __restrict__ attn, float* __restrict__ probs_f)
{
    __shared__ alignas(16) bf16 As[2 * 4096];
    __shared__ alignas(16) bf16 Bs[2 * 8192];
    __shared__ float rs[64];
    const int tid = threadIdx.x;
    const int lane = tid & 63, wave = tid >> 6, l15 = lane & 15, quad = lane >> 4;

    int lin = blockIdx.x + 8 * blockIdx.y;      // 0..255 (per z)
    int c = lin & 7, s = lin >> 3;              // c = XCD slot, s = 0..31
    const int nx = s >> 2;                      // n-tile AND probs k-slice index (0..7)
    const int n0 = nx * 128;
    const int m0 = (c * 4 + (s & 3)) * 64;      // y-tile 0..31 (bijective)
    const int z  = blockIdx.z;
    const int WM = (wave >> 2) * 32, WN = (wave & 3) * 32;

    const bf16* Ab = pb + (long long)z * 4194304LL;
    const bf16* Wb = vt + (long long)z * 2097152LL;

    // kick off tile-0 loads, then compute rs while they fly
    stage_ab64(Ab, 2048, Wb, 2048, m0, n0, 0, wave, lane, As, Bs);

    // prologue: rs[r] = 1 / sum_j spart[z*2048+m0+r][j]  (64 rows, 8 threads per row)
    {
        int r = tid >> 3, part = tid & 7;
        const float* sp = spart + ((long long)z * 2048 + m0 + r) * 32 + part * 4;
        float4 a = *reinterpret_cast<const float4*>(sp);
        float v = a.x + a.y + a.z + a.w;
        v += __shfl_xor(v, 1, 64);
        v += __shfl_xor(v, 2, 64);
        v += __shfl_xor(v, 4, 64);
        if (part == 0) rs[r] = 1.0f / v;
    }

    f32_4 acc[2][2];
#pragma unroll
    for (int i = 0; i < 2; i++)
#pragma unroll
        for (int j = 0; j < 2; j++) acc[i][j] = (f32_4)(0.0f);

    for (int t = 0; t < 32; ++t) {
        const int cur = t & 1;
        if (t + 1 < 32) {
            stage_ab64(Ab, 2048, Wb, 2048, m0, n0, (t + 1) * 64, wave, lane,
                       As + (cur ^ 1) * 4096, Bs + (cur ^ 1) * 8192);
            asm volatile("s_waitcnt vmcnt(3)" ::: "memory");
        } else {
            asm volatile("s_waitcnt vmcnt(0)" ::: "memory");
        }
        __builtin_amdgcn_s_barrier();   // tile t ready (all waves); also publishes rs at t=0

        // write probs_f (f32, normalized) when this k-64 tile is in our 256-col k-slice
        if ((t >> 2) == nx) {
            const bf16* Asu = As + cur * 4096;
            int s2 = tid;                    // 512 threads cover 64x64 tile (8 bf16 each)
            int r = s2 >> 3, q = s2 & 7;
            bf16_8 e = *reinterpret_cast<const bf16_8*>(&Asu[r * 64 + (q ^ (r & 7)) * 8]);
            float inv = rs[r];
            float4 o0, o1;
            o0.x = (float)e[0] * inv; o0.y = (float)e[1] * inv;
            o0.z = (float)e[2] * inv; o0.w = (float)e[3] * inv;
            o1.x = (float)e[4] * inv; o1.y = (float)e[5] * inv;
            o1.z = (float)e[6] * inv; o1.w = (float)e[7] * inv;
            long long base = ((long long)z * 2048 + m0 + r) * 2048 + t * 64 + q * 8;
            *reinterpret_cast<float4*>(&probs_f[base])     = o0;
            *reinterpret_cast<float4*>(&probs_f[base + 4]) = o1;
        }

        mma64(As + cur * 4096, Bs + cur * 8192, WM, WN, l15, quad, acc);

        asm volatile("s_waitcnt lgkmcnt(0)" ::: "memory");
        __builtin_amdgcn_s_barrier();
    }

    // epilogue: scale by rs[row], scatter to flat attn layout
    long long obase = (long long)z * 2097152LL;
#pragma unroll
    for (int i = 0; i < 2; i++)
#pragma unroll
        for (int j = 0; j < 2; j++)
#pragma unroll
            for (int rg = 0; rg < 4; rg++) {
                int ml = WM + i * 16 + quad * 4 + rg;
                int m = m0 + ml;
                int n = n0 + WN + j * 16 + l15;
                float v = acc[i][j][rg] * rs[ml];
                long long off = obase + ((long long)(n >> 6)) * 131072LL + (long long)m * 64 + (n & 63);
                attn[off] = (bf16)v;
            }
}

// -------- out projection: 2-phase DB, counted vmcnt; f32 out + bias --------
// XCD-aware tile remap: XCD c owns y' = c*8 + (s&7), x' = s>>3
__global__ __launch_bounds__(512) void out_proj(
    const bf16* __restrict__ attn, const bf16* __restrict__ wo_bf,
    const float* __restrict__ bo, float* __restrict__ out_f)
{
    __shared__ alignas(16) bf16 As[2 * 4096];
    __shared__ alignas(16) bf16 Bs[2 * 8192];
    const int tid = threadIdx.x;
    const int lane = tid & 63, wave = tid >> 6, l15 = lane & 15, quad = lane >> 4;

    int lin = blockIdx.x + 8 * blockIdx.y;      // 0..511
    int c = lin & 7, s = lin >> 3;              // s = 0..63
    const int n0 = (s >> 3) * 128;
    const int m0 = (c * 8 + (s & 7)) * 64;      // y-tile 0..63 (bijective)

    f32_4 acc[2][2];
    gemm_db64<16>(attn, 1024, wo_bf, 1024, m0, n0, tid, As, Bs, acc);

    const int WM = (wave >> 2) * 32;
    const int WN = (wave & 3) * 32;
#pragma unroll
    for (int i = 0; i < 2; i++)
#pragma unroll
        for (int j = 0; j < 2; j++)
#pragma unroll
            for (int rg = 0; rg < 4; rg++) {
                int m = m0 + WM + i * 16 + quad * 4 + rg;
                int n = n0 + WN + j * 16 + l15;
                out_f[(long long)m * 1024 + n] = acc[i][j][rg] + bo[n];
            }
}

// ---------------- launcher: 5 launches ----------------
extern "C" void kernel_launch(void* const* d_in, const int* in_sizes, int n_in,
                              void* d_out, int out_size, void* d_ws, size_t ws_size,
                              hipStream_t stream) {
    const float* x      = (const float*)d_in[0];
    const float* Wq     = (const float*)d_in[1];
    const float* bq     = (const float*)d_in[2];
    const float* Wk     = (const float*)d_in[3];
    const float* bk     = (const float*)d_in[4];
    const float* Wv     = (const float*)d_in[5];
    const float* bv     = (const float*)d_in[6];
    const float* Wo     = (const float*)d_in[7];
    const float* bo     = (const float*)d_in[8];
    const float* slopes = (const float*)d_in[9];

    // B=2, S=2048, E=1024, H=16, hd=64
    char* w = (char*)d_ws;
    bf16* x_bf  = (bf16*)w;  w += 4096LL * 1024 * 2;
    bf16* wq_bf = (bf16*)w;  w += 1024LL * 1024 * 2;
    bf16* wk_bf = (bf16*)w;  w += 1024LL * 1024 * 2;
    bf16* wv_bf = (bf16*)w;  w += 1024LL * 1024 * 2;
    bf16* wo_bf = (bf16*)w;  w += 1024LL * 1024 * 2;
    bf16* qh1   = (bf16*)w;  w += 2LL * 131072 * 2;
    bf16* kh1   = (bf16*)w;  w += 2LL * 131072 * 2;
    bf16* v_bf  = (bf16*)w;  w += 4096LL * 1024 * 2;
    bf16* vt    = (bf16*)w;  w += 2LL * 1024 * 2048 * 2;
    bf16* attn  = (bf16*)w;  w += 4096LL * 1024 * 2;
    bf16* pb    = (bf16*)w;  w += 2LL * 2048 * 2048 * 2;
    float* spart = (float*)w; w += 4096LL * 32 * 4;

    float* out_f   = (float*)d_out;                // (B,S,E)
    float* probs_f = (float*)d_out + 4194304LL;    // (B,1,S,S)

    // 1) converts
    convert_all<<<2048, 256, 0, stream>>>(x, Wq, Wk, Wv, Wo, x_bf, wq_bf, wk_bf, wv_bf, wo_bf);

    // 2) merged projections: V full + Q/K head-1 (2-phase DB, XCD remap)
    proj_merged<<<dim3(8, 72, 1), 512, 0, stream>>>(
        x_bf, wv_bf, bv, v_bf, wq_bf, bq, qh1, wk_bf, bk, kh1);

    // 3) scores + exp + spart, then inline V transpose
    scores_tr<<<dim3(16, 16, 2), 256, 0, stream>>>(
        qh1, kh1, slopes, pb, spart,
        (const unsigned short*)v_bf, (unsigned short*)vt);

    // 4) PV fused: 2-phase DB, XCD remap; rsinv from spart, probs_f (d_out), attn scatter
    pv_fused<<<dim3(8, 32, 2), 512, 0, stream>>>(pb, vt, spart, attn, probs_f);

    // 5) out projection -> d_out (2-phase DB, XCD remap)
    out_proj<<<dim3(8, 64, 1), 512, 0, stream>>>(attn, wo_bf, bo, out_f);
}

// Round 7
// 167.876 us; speedup vs baseline: 1.1375x; 1.0032x over previous
//
#include <hip/hip_runtime.h>

typedef __bf16 bf16;
typedef __bf16 bf16_4 __attribute__((ext_vector_type(4)));
typedef __bf16 bf16_8 __attribute__((ext_vector_type(8)));
typedef float f32_4 __attribute__((ext_vector_type(4)));

// async global->LDS, 16B per lane; LDS dest must be wave-uniform base + lane*16
#define GLDS16(g, l) \
  __builtin_amdgcn_global_load_lds((const __attribute__((address_space(1))) unsigned int*)(g), \
                                   (__attribute__((address_space(3))) unsigned int*)(l), 16, 0, 0)

// ---------------- fused f32 -> bf16 convert (grid-stride) ----------------
__global__ __launch_bounds__(256) void convert_all(
    const float* __restrict__ x, const float* __restrict__ wq, const float* __restrict__ wk,
    const float* __restrict__ wv, const float* __restrict__ wo,
    bf16* __restrict__ xb, bf16* __restrict__ wqb, bf16* __restrict__ wkb,
    bf16* __restrict__ wvb, bf16* __restrict__ wob)
{
    for (int i = blockIdx.x * 256 + threadIdx.x; i < 2097152; i += 2048 * 256) {
        const float* s; bf16* d; int off;
        if (i < 1048576) { s = x; d = xb; off = i; }
        else {
            int j = i - 1048576;
            int sel = j >> 18;
            off = j & 262143;
            s = (sel == 0) ? wq : (sel == 1) ? wk : (sel == 2) ? wv : wo;
            d = (sel == 0) ? wqb : (sel == 1) ? wkb : (sel == 2) ? wvb : wob;
        }
        float4 v = reinterpret_cast<const float4*>(s)[off];
        bf16_4 o; o.x = (bf16)v.x; o.y = (bf16)v.y; o.z = (bf16)v.z; o.w = (bf16)v.w;
        reinterpret_cast<bf16_4*>(d)[off] = o;
    }
}

// ---- legacy single-buffer GEMM core (used by scores_tr only: BM=128, KU=1, NW=4) ----
template<int BM, int KU, int NW>
__device__ __forceinline__ void gemm_core(
    const bf16* __restrict__ Ab, int lda,
    const bf16* __restrict__ Wb, int ldw,
    int K, int m0, int n0, int tid,
    bf16* As, bf16* Bs,
    f32_4 (&acc)[(BM == 128) ? 4 : 2][(BM == 128) ? 4 : 2])
{
    constexpr int MI = (BM == 128) ? 4 : 2;
    constexpr int NJ = (BM == 128) ? 4 : 2;
    constexpr int ITA = (BM * 8) / (NW * 64);     // A 16B-groups per lane per ku
    constexpr int ITB = 1024 / (NW * 64);         // B 16B-groups per lane per ku
    const int lane = tid & 63;
    const int wave = tid >> 6;
    const int l15  = lane & 15;
    const int quad = lane >> 4;
    const int WM = (BM == 128) ? (wave >> 1) * 64 : (wave >> 2) * 32;
    const int WN = (BM == 128) ? (wave & 1) * 64 : (wave & 3) * 32;

#pragma unroll
    for (int i = 0; i < MI; i++)
#pragma unroll
        for (int j = 0; j < NJ; j++) acc[i][j] = (f32_4)(0.0f);

    for (int k0 = 0; k0 < K; k0 += 64 * KU) {
#pragma unroll
        for (int ku = 0; ku < KU; ++ku) {
            bf16* Asu = As + ku * BM * 64;
            bf16* Bsu = Bs + ku * 128 * 64;
            int kk = k0 + ku * 64;
#pragma unroll
            for (int it = 0; it < ITA; ++it) {
                int p = wave * (BM * 8 / NW) + it * 64 + lane;
                int r = p >> 3;
                int q = (p & 7) ^ (r & 7);
                GLDS16(Ab + (long long)(m0 + r) * lda + kk + q * 8, Asu + p * 8);
            }
#pragma unroll
            for (int it = 0; it < ITB; ++it) {
                int p = wave * (1024 / NW) + it * 64 + lane;
                int r = p >> 3;
                int q = (p & 7) ^ (r & 7);
                GLDS16(Wb + (long long)(n0 + r) * ldw + kk + q * 8, Bsu + p * 8);
            }
        }
        __syncthreads();

#pragma unroll
        for (int ku = 0; ku < KU; ++ku) {
            bf16* Asu = As + ku * BM * 64;
            bf16* Bsu = Bs + ku * 128 * 64;
#pragma unroll
            for (int kh = 0; kh < 2; ++kh) {
                bf16_8 af[MI], bfr[NJ];
#pragma unroll
                for (int t = 0; t < MI; ++t) {
                    int r = WM + t * 16 + l15;
                    int q = (kh * 4 + quad) ^ (r & 7);
                    af[t] = *reinterpret_cast<const bf16_8*>(&Asu[r * 64 + q * 8]);
                }
#pragma unroll
                for (int j = 0; j < NJ; ++j) {
                    int r = WN + j * 16 + l15;
                    int q = (kh * 4 + quad) ^ (r & 7);
                    bfr[j] = *reinterpret_cast<const bf16_8*>(&Bsu[r * 64 + q * 8]);
                }
#pragma unroll
                for (int i = 0; i < MI; ++i)
#pragma unroll
                    for (int j = 0; j < NJ; ++j)
                        acc[i][j] = __builtin_amdgcn_mfma_f32_16x16x32_bf16(af[i], bfr[j], acc[i][j], 0, 0, 0);
            }
        }
        __syncthreads();
    }
}

// ======== 2-phase double-buffered 64x128 GEMM pieces (8 waves, wave-tile 32x32) ========
// Per buffer: As 64x64 (8KB), Bs 128x64 (16KB).  3 GLDS16 per wave per k-64 tile.
__device__ __forceinline__ void stage_ab64(
    const bf16* __restrict__ Ab, long long lda,
    const bf16* __restrict__ Wb, long long ldw,
    int m0, int n0, int kk, int wave, int lane,
    bf16* Asb, bf16* Bsb)
{
    {
        int p = wave * 64 + lane;                 // 512 slots x 8 bf16 = 64x64
        int r = p >> 3, q = (p & 7) ^ (r & 7);
        GLDS16(Ab + (long long)(m0 + r) * lda + kk + q * 8, Asb + p * 8);
    }
#pragma unroll
    for (int it = 0; it < 2; ++it) {
        int p = wave * 128 + it * 64 + lane;      // 1024 slots x 8 bf16 = 128x64
        int r = p >> 3, q = (p & 7) ^ (r & 7);
        GLDS16(Wb + (long long)(n0 + r) * ldw + kk + q * 8, Bsb + p * 8);
    }
}

__device__ __forceinline__ void mma64(
    const bf16* Asb, const bf16* Bsb, int WM, int WN, int l15, int quad,
    f32_4 (&acc)[2][2])
{
#pragma unroll
    for (int kh = 0; kh < 2; ++kh) {
        bf16_8 af[2], bfr[2];
#pragma unroll
        for (int t = 0; t < 2; ++t) {
            int r = WM + t * 16 + l15;
            int q = (kh * 4 + quad) ^ (r & 7);
            af[t] = *reinterpret_cast<const bf16_8*>(&Asb[r * 64 + q * 8]);
        }
#pragma unroll
        for (int j = 0; j < 2; ++j) {
            int r = WN + j * 16 + l15;
            int q = (kh * 4 + quad) ^ (r & 7);
            bfr[j] = *reinterpret_cast<const bf16_8*>(&Bsb[r * 64 + q * 8]);
        }
#pragma unroll
        for (int i = 0; i < 2; ++i)
#pragma unroll
            for (int j = 0; j < 2; ++j)
                acc[i][j] = __builtin_amdgcn_mfma_f32_16x16x32_bf16(af[i], bfr[j], acc[i][j], 0, 0, 0);
    }
}

// full double-buffered K-loop: NT k-64 tiles, counted vmcnt(3) keeps next tile in flight
// T5: setprio(1) around the MFMA cluster (2-phase role diversity across blocks/CU)
template<int NT>
__device__ __forceinline__ void gemm_db64(
    const bf16* __restrict__ Ab, long long lda,
    const bf16* __restrict__ Wb, long long ldw,
    int m0, int n0, int tid, bf16* As, bf16* Bs,   // As[2][4096], Bs[2][8192]
    f32_4 (&acc)[2][2])
{
    const int lane = tid & 63, wave = tid >> 6, l15 = lane & 15, quad = lane >> 4;
    const int WM = (wave >> 2) * 32, WN = (wave & 3) * 32;
#pragma unroll
    for (int i = 0; i < 2; i++)
#pragma unroll
        for (int j = 0; j < 2; j++) acc[i][j] = (f32_4)(0.0f);

    stage_ab64(Ab, lda, Wb, ldw, m0, n0, 0, wave, lane, As, Bs);
    for (int t = 0; t < NT; ++t) {
        const int cur = t & 1;
        if (t + 1 < NT) {
            stage_ab64(Ab, lda, Wb, ldw, m0, n0, (t + 1) * 64, wave, lane,
                       As + (cur ^ 1) * 4096, Bs + (cur ^ 1) * 8192);
            asm volatile("s_waitcnt vmcnt(3)" ::: "memory");   // tile t landed; t+1 in flight
        } else {
            asm volatile("s_waitcnt vmcnt(0)" ::: "memory");
        }
        __builtin_amdgcn_s_barrier();
        __builtin_amdgcn_s_setprio(1);
        mma64(As + cur * 4096, Bs + cur * 8192, WM, WN, l15, quad, acc);
        __builtin_amdgcn_s_setprio(0);
        asm volatile("s_waitcnt lgkmcnt(0)" ::: "memory");     // my LDS reads done
        __builtin_amdgcn_s_barrier();                          // buf may be overwritten
    }
}

// -------- merged projections: V full + Q/K head-1 (2-phase DB, 512 thr / 8 waves) -----
// XCD-aware tile remap: lin = x + 8y (XCD = lin&7); XCD c owns y' = c*9 + (s%9), x' = s/9
// so the 8 blocks sharing an A-panel (same y', all x') colocate on one XCD L2.
__global__ __launch_bounds__(512) void proj_merged(
    const bf16* __restrict__ x_bf,
    const bf16* __restrict__ wv_bf, const float* __restrict__ bv, bf16* __restrict__ v_bf,
    const bf16* __restrict__ wq_bf, const float* __restrict__ bq, bf16* __restrict__ qh1,
    const bf16* __restrict__ wk_bf, const float* __restrict__ bk, bf16* __restrict__ kh1)
{
    __shared__ alignas(16) bf16 As[2 * 4096];
    __shared__ alignas(16) bf16 Bs[2 * 8192];
    const int tid = threadIdx.x;
    const int lane = tid & 63, wave = tid >> 6, l15 = lane & 15, quad = lane >> 4;

    int lin = blockIdx.x + 8 * blockIdx.y;      // 0..575
    int c = lin & 7, s = lin >> 3;              // c = XCD slot, s = 0..71
    int y = c * 9 + (s % 9);                    // 0..71 (bijective)
    const int n0 = (s / 9) * 128;               // 0..7 -> n-tile

    int m0;
    const bf16* Ab; const bf16* Wb; const float* bvec; bf16* op;
    long long obase;
    if (y < 64) { m0 = y * 64; Ab = x_bf; Wb = wv_bf; bvec = bv; op = v_bf; obase = 0; }
    else {
        int sub = y - 64;
        int batch = (sub >> 1) & 1;
        int sel = sub >> 2;
        m0 = (sub & 1) * 64;
        Ab = x_bf + (long long)batch * 2097152LL + 131072LL;   // rows 128..255 of batch slab
        Wb = sel ? wk_bf : wq_bf;
        bvec = sel ? bk : bq;
        op = sel ? kh1 : qh1;
        obase = (long long)batch * 131072LL;
    }

    f32_4 acc[2][2];
    gemm_db64<16>(Ab, 1024, Wb, 1024, m0, n0, tid, As, Bs, acc);

    const int WM = (wave >> 2) * 32;
    const int WN = (wave & 3) * 32;
#pragma unroll
    for (int i = 0; i < 2; i++)
#pragma unroll
        for (int j = 0; j < 2; j++)
#pragma unroll
            for (int rg = 0; rg < 4; rg++) {
                int m = m0 + WM + i * 16 + quad * 4 + rg;
                int n = n0 + WN + j * 16 + l15;
                op[obase + (long long)m * 1024 + n] = (bf16)(acc[i][j][rg] + bvec[n]);
            }
}

// -------- scores head-1 + exp + row partials, THEN inline V transpose (BK=64, K=64) ---
__global__ __launch_bounds__(256) void scores_tr(
    const bf16* __restrict__ qh1, const bf16* __restrict__ kh1,
    const float* __restrict__ slopes,
    bf16* __restrict__ pb, float* __restrict__ spart,
    const unsigned short* __restrict__ v_bf, unsigned short* __restrict__ vt)
{
    __shared__ alignas(16) char smem[32768];
    bf16* As = (bf16*)smem;
    bf16* Bs = (bf16*)(smem + 16384);
    const int tid = threadIdx.x;
    const int lane = tid & 63, wave = tid >> 6, l15 = lane & 15, quad = lane >> 4;
    const int n0 = blockIdx.x * 128;
    const int m0 = blockIdx.y * 128;
    const int z  = blockIdx.z;

    f32_4 acc[4][4];
    gemm_core<128, 1, 4>(qh1 + (long long)z * 131072LL, 64,
                         kh1 + (long long)z * 131072LL, 64, 64, m0, n0, tid, As, Bs, acc);

    const int WM = (wave >> 1) * 64;
    const int WN = (wave & 1) * 64;
    const float slope = slopes[1];
    long long obase = (long long)z * 4194304LL;
#pragma unroll
    for (int i = 0; i < 4; i++) {
#pragma unroll
        for (int rg = 0; rg < 4; rg++) {
            int m = m0 + WM + i * 16 + quad * 4 + rg;
            float rowpart = 0.0f;
#pragma unroll
            for (int j = 0; j < 4; j++) {
                int n = n0 + WN + j * 16 + l15;
                float v = acc[i][j][rg] * 0.125f - slope * fabsf((float)(m - n));
                float e = __expf(v);
                rowpart += e;
                pb[obase + (long long)m * 2048 + n] = (bf16)e;
            }
            rowpart += __shfl_xor(rowpart, 1, 64);
            rowpart += __shfl_xor(rowpart, 2, 64);
            rowpart += __shfl_xor(rowpart, 4, 64);
            rowpart += __shfl_xor(rowpart, 8, 64);
            if (l15 == 0)
                spart[((long long)z * 2048 + m) * 32 + (n0 >> 6) + (WN >> 6)] = rowpart;
        }
    }

    // ---- inline V transpose (flat-reshape mapping), 2 of 1024 tiles per block ----
    unsigned short* tile = (unsigned short*)smem;    // As region free after gemm_core
    int flat = z * 256 + blockIdx.y * 16 + blockIdx.x;   // 0..511
#pragma unroll
    for (int uu = 0; uu < 2; ++uu) {
        int u = flat * 2 + uu;                           // 0..1023
        int k0 = (u & 31) * 64, h = (u >> 5) & 15, b = u >> 9;
        const unsigned short* src = v_bf + (long long)b * 2097152LL + (long long)h * 131072LL;
#pragma unroll
        for (int p = 0; p < 8; p++) {
            int idx = tid + p * 256;
            int k = idx >> 5, dc = idx & 31;
            ushort2 w = *reinterpret_cast<const ushort2*>(&src[(long long)(k0 + k) * 64 + dc * 2]);
            tile[(dc * 2) * 66 + k]     = w.x;
            tile[(dc * 2 + 1) * 66 + k] = w.y;
        }
        __syncthreads();
        unsigned short* dst = vt + (long long)b * 2097152LL + (long long)h * 64 * 2048LL + k0;
#pragma unroll
        for (int p = 0; p < 8; p++) {
            int idx = tid + p * 256;
            int d = idx >> 5, kc = idx & 31;
            ushort2 w;
            w.x = tile[d * 66 + kc * 2];
            w.y = tile[d * 66 + kc * 2 + 1];
            *reinterpret_cast<ushort2*>(&dst[(long long)d * 2048 + kc * 2]) = w;
        }
        __syncthreads();
    }
}

// -------- PV fused: 2-phase DB, counted vmcnt; rsinv prologue + probs_f in-loop -------
// XCD-aware tile remap: lin = x + 8y (XCD = lin&7); XCD c owns y' = c*4 + (s&3), x' = s>>2
// probs_f write moved AFTER the MFMA cluster (stores overlap lgkm/barrier/stage window)
__global__ __launch_bounds__(512) void pv_fused(
    const bf16* __restrict__ pb, const bf16* __restrict__ vt,
    const float* __restrict__ spart,
    bf16* __restrict__ attn, float* __restrict__ probs_f)
{
    __shared__ alignas(16) bf16 As[2 * 4096];
    __shared__ alignas(16) bf16 Bs[2 * 8192];
    __shared__ float rs[64];
    const int tid = threadIdx.x;
    const int lane = tid & 63, wave = tid >> 6, l15 = lane & 15, quad = lane >> 4;

    int lin = blockIdx.x + 8 * blockIdx.y;      // 0..255 (per z)
    int c = lin & 7, s = lin >> 3;              // c = XCD slot, s = 0..31
    const int nx = s >> 2;                      // n-tile AND probs k-slice index (0..7)
    const int n0 = nx * 128;
    const int m0 = (c * 4 + (s & 3)) * 64;      // y-tile 0..31 (bijective)
    const int z  = blockIdx.z;
    const int WM = (wave >> 2) * 32, WN = (wave & 3) * 32;

    const bf16* Ab = pb + (long long)z * 4194304LL;
    const bf16* Wb = vt + (long long)z * 2097152LL;

    // kick off tile-0 loads, then compute rs while they fly
    stage_ab64(Ab, 2048, Wb, 2048, m0, n0, 0, wave, lane, As, Bs);

    // prologue: rs[r] = 1 / sum_j spart[z*2048+m0+r][j]  (64 rows, 8 threads per row)
    {
        int r = tid >> 3, part = tid & 7;
        const float* sp = spart + ((long long)z * 2048 + m0 + r) * 32 + part * 4;
        float4 a = *reinterpret_cast<const float4*>(sp);
        float v = a.x + a.y + a.z + a.w;
        v += __shfl_xor(v, 1, 64);
        v += __shfl_xor(v, 2, 64);
        v += __shfl_xor(v, 4, 64);
        if (part == 0) rs[r] = 1.0f / v;
    }

    f32_4 acc[2][2];
#pragma unroll
    for (int i = 0; i < 2; i++)
#pragma unroll
        for (int j = 0; j < 2; j++) acc[i][j] = (f32_4)(0.0f);

    for (int t = 0; t < 32; ++t) {
        const int cur = t & 1;
        if (t + 1 < 32) {
            stage_ab64(Ab, 2048, Wb, 2048, m0, n0, (t + 1) * 64, wave, lane,
                       As + (cur ^ 1) * 4096, Bs + (cur ^ 1) * 8192);
            asm volatile("s_waitcnt vmcnt(3)" ::: "memory");
        } else {
            asm volatile("s_waitcnt vmcnt(0)" ::: "memory");
        }
        __builtin_amdgcn_s_barrier();   // tile t ready (all waves); also publishes rs at t=0

        __builtin_amdgcn_s_setprio(1);
        mma64(As + cur * 4096, Bs + cur * 8192, WM, WN, l15, quad, acc);
        __builtin_amdgcn_s_setprio(0);

        // write probs_f (f32, normalized) when this k-64 tile is in our 256-col k-slice
        // (after MFMA: stores + their LDS reads overlap the lgkm/barrier/stage window)
        if ((t >> 2) == nx) {
            const bf16* Asu = As + cur * 4096;
            int s2 = tid;                    // 512 threads cover 64x64 tile (8 bf16 each)
            int r = s2 >> 3, q = s2 & 7;
            bf16_8 e = *reinterpret_cast<const bf16_8*>(&Asu[r * 64 + (q ^ (r & 7)) * 8]);
            float inv = rs[r];
            float4 o0, o1;
            o0.x = (float)e[0] * inv; o0.y = (float)e[1] * inv;
            o0.z = (float)e[2] * inv; o0.w = (float)e[3] * inv;
            o1.x = (float)e[4] * inv; o1.y = (float)e[5] * inv;
            o1.z = (float)e[6] * inv; o1.w = (float)e[7] * inv;
            long long base = ((long long)z * 2048 + m0 + r) * 2048 + t * 64 + q * 8;
            *reinterpret_cast<float4*>(&probs_f[base])     = o0;
            *reinterpret_cast<float4*>(&probs_f[base + 4]) = o1;
        }

        asm volatile("s_waitcnt lgkmcnt(0)" ::: "memory");
        __builtin_amdgcn_s_barrier();
    }

    // epilogue: scale by rs[row], scatter to flat attn layout
    long long obase = (long long)z * 2097152LL;
#pragma unroll
    for (int i = 0; i < 2; i++)
#pragma unroll
        for (int j = 0; j < 2; j++)
#pragma unroll
            for (int rg = 0; rg < 4; rg++) {
                int ml = WM + i * 16 + quad * 4 + rg;
                int m = m0 + ml;
                int n = n0 + WN + j * 16 + l15;
                float v = acc[i][j][rg] * rs[ml];
                long long off = obase + ((long long)(n >> 6)) * 131072LL + (long long)m * 64 + (n & 63);
                attn[off] = (bf16)v;
            }
}

// -------- out projection: 2-phase DB, counted vmcnt; f32 out + bias --------
// XCD-aware tile remap: XCD c owns y' = c*8 + (s&7), x' = s>>3
__global__ __launch_bounds__(512) void out_proj(
    const bf16* __restrict__ attn, const bf16* __restrict__ wo_bf,
    const float* __restrict__ bo, float* __restrict__ out_f)
{
    __shared__ alignas(16) bf16 As[2 * 4096];
    __shared__ alignas(16) bf16 Bs[2 * 8192];
    const int tid = threadIdx.x;
    const int lane = tid & 63, wave = tid >> 6, l15 = lane & 15, quad = lane >> 4;

    int lin = blockIdx.x + 8 * blockIdx.y;      // 0..511
    int c = lin & 7, s = lin >> 3;              // s = 0..63
    const int n0 = (s >> 3) * 128;
    const int m0 = (c * 8 + (s & 7)) * 64;      // y-tile 0..63 (bijective)

    f32_4 acc[2][2];
    gemm_db64<16>(attn, 1024, wo_bf, 1024, m0, n0, tid, As, Bs, acc);

    const int WM = (wave >> 2) * 32;
    const int WN = (wave & 3) * 32;
#pragma unroll
    for (int i = 0; i < 2; i++)
#pragma unroll
        for (int j = 0; j < 2; j++)
#pragma unroll
            for (int rg = 0; rg < 4; rg++) {
                int m = m0 + WM + i * 16 + quad * 4 + rg;
                int n = n0 + WN + j * 16 + l15;
                out_f[(long long)m * 1024 + n] = acc[i][j][rg] + bo[n];
            }
}

// ---------------- launcher: 5 launches ----------------
extern "C" void kernel_launch(void* const* d_in, const int* in_sizes, int n_in,
                              void* d_out, int out_size, void* d_ws, size_t ws_size,
                              hipStream_t stream) {
    const float* x      = (const float*)d_in[0];
    const float* Wq     = (const float*)d_in[1];
    const float* bq     = (const float*)d_in[2];
    const float* Wk     = (const float*)d_in[3];
    const float* bk     = (const float*)d_in[4];
    const float* Wv     = (const float*)d_in[5];
    const float* bv     = (const float*)d_in[6];
    const float* Wo     = (const float*)d_in[7];
    const float* bo     = (const float*)d_in[8];
    const float* slopes = (const float*)d_in[9];

    // B=2, S=2048, E=1024, H=16, hd=64
    char* w = (char*)d_ws;
    bf16* x_bf  = (bf16*)w;  w += 4096LL * 1024 * 2;
    bf16* wq_bf = (bf16*)w;  w += 1024LL * 1024 * 2;
    bf16* wk_bf = (bf16*)w;  w += 1024LL * 1024 * 2;
    bf16* wv_bf = (bf16*)w;  w += 1024LL * 1024 * 2;
    bf16* wo_bf = (bf16*)w;  w += 1024LL * 1024 * 2;
    bf16* qh1   = (bf16*)w;  w += 2LL * 131072 * 2;
    bf16* kh1   = (bf16*)w;  w += 2LL * 131072 * 2;
    bf16* v_bf  = (bf16*)w;  w += 4096LL * 1024 * 2;
    bf16* vt    = (bf16*)w;  w += 2LL * 1024 * 2048 * 2;
    bf16* attn  = (bf16*)w;  w += 4096LL * 1024 * 2;
    bf16* pb    = (bf16*)w;  w += 2LL * 2048 * 2048 * 2;
    float* spart = (float*)w; w += 4096LL * 32 * 4;

    float* out_f   = (float*)d_out;                // (B,S,E)
    float* probs_f = (float*)d_out + 4194304LL;    // (B,1,S,S)

    // 1) converts
    convert_all<<<2048, 256, 0, stream>>>(x, Wq, Wk, Wv, Wo, x_bf, wq_bf, wk_bf, wv_bf, wo_bf);

    // 2) merged projections: V full + Q/K head-1 (2-phase DB, XCD remap, T5)
    proj_merged<<<dim3(8, 72, 1), 512, 0, stream>>>(
        x_bf, wv_bf, bv, v_bf, wq_bf, bq, qh1, wk_bf, bk, kh1);

    // 3) scores + exp + spart, then inline V transpose
    scores_tr<<<dim3(16, 16, 2), 256, 0, stream>>>(
        qh1, kh1, slopes, pb, spart,
        (const unsigned short*)v_bf, (unsigned short*)vt);

    // 4) PV fused: 2-phase DB, XCD remap, T5; rsinv, probs_f (d_out), attn scatter
    pv_fused<<<dim3(8, 32, 2), 512, 0, stream>>>(pb, vt, spart, attn, probs_f);

    // 5) out projection -> d_out (2-phase DB, XCD remap, T5)
    out_proj<<<dim3(8, 64, 1), 512, 0, stream>>>(attn, wo_bf, bo, out_f);
}